// Round 8
// baseline (424.424 us; speedup 1.0000x reference)
//
#include <hip/hip_runtime.h>
#include <stdint.h>

#define B_ 1024
#define D_ 784
#define H_ 1024
#define BH_ (B_ * H_)
#define LOG2E 1.4426950408889634f

// Segments: {0,132,264,396,528,656,784} (all %4). G ranges: first 5 spans.
// VWs image layout per (step i, hb): 512 floats =
//   [blk0: V h(0..3) by hl][blk1: V h(4..7)][blk2: W h(0..3)][blk3: W h(4..7)],
//   each blk = 32 hl * 4 floats  -> lane reads 4x b128 at hl*16B + blk*512B (conflict-free).
// ws: VWs [792][4][512] 6.49 MB | G [5][B][H] 21 MB | part [4][B][D] 12.8 MB

typedef float v2f __attribute__((ext_vector_type(2)));

__device__ __forceinline__ v2f pk_fma(v2f a, v2f b, v2f c) {
    v2f d; asm("v_pk_fma_f32 %0, %1, %2, %3" : "=v"(d) : "v"(a), "v"(b), "v"(c)); return d;
}
__device__ __forceinline__ v2f pk_add(v2f a, v2f b) {
    v2f d; asm("v_pk_add_f32 %0, %1, %2" : "=v"(d) : "v"(a), "v"(b)); return d;
}
__device__ __forceinline__ v2f pk_sub(v2f a, v2f b) {
    v2f d; asm("v_pk_add_f32 %0, %1, %2 neg_lo:[0,1] neg_hi:[0,1]" : "=v"(d) : "v"(a), "v"(b)); return d;
}
__device__ __forceinline__ v2f pk_mul(v2f a, v2f b) {
    v2f d; asm("v_pk_mul_f32 %0, %1, %2" : "=v"(d) : "v"(a), "v"(b)); return d;
}

// packed exp2, t pre-clamped to [-126, 15]
__device__ __forceinline__ v2f exp2_pk(v2f t) {
    const v2f MG = {12582912.f, 12582912.f};   // 1.5 * 2^23
    v2f m = pk_add(t, MG);
    v2f n = pk_sub(m, MG);
    v2f f = pk_sub(t, n);
    v2f p = {0.0013333558f, 0.0013333558f};
    p = pk_fma(p, f, (v2f){0.0096181291f, 0.0096181291f});
    p = pk_fma(p, f, (v2f){0.0555041087f, 0.0555041087f});
    p = pk_fma(p, f, (v2f){0.2402265070f, 0.2402265070f});
    p = pk_fma(p, f, (v2f){0.6931471806f, 0.6931471806f});
    p = pk_fma(p, f, (v2f){1.0f, 1.0f});
    v2f s;
    s.x = __uint_as_float((__float_as_uint(m.x) << 23) + 0x3F800000u);
    s.y = __uint_as_float((__float_as_uint(m.y) << 23) + 0x3F800000u);
    return pk_mul(s, p);
}

__device__ __forceinline__ int seg_bound(int s) {
    const int b[7] = {0, 132, 264, 396, 528, 656, 784};
    return b[s];
}

// VWs float index for V element (i,h); W: +256 within the same image
__device__ __forceinline__ size_t vw_idx(int i, int h) {
    return ((size_t)i * 4 + (h >> 8)) * 512 + ((h >> 2) & 1) * 128 + (((h & 255) >> 3) * 4) + (h & 3);
}

// ---------- fat prep ----------
__global__ __launch_bounds__(256) void prep(const float* __restrict__ V,
                                            const float* __restrict__ W,
                                            const float* __restrict__ px,
                                            float* __restrict__ VWs,
                                            float* __restrict__ G) {
    __shared__ float smem[32 * 33];
    const int t = threadIdx.x;

    if (blockIdx.x < 800) {
        int i0 = (blockIdx.x % 25) * 32;
        int h0 = (blockIdx.x / 25) * 32;
        int tx = t & 31, ty = t >> 5;   // 32 x 8
        // V scatter into image layout
#pragma unroll
        for (int j = 0; j < 4; ++j) {
            int i = i0 + ty + j * 8;
            int h = h0 + tx;
            if (i < D_) VWs[vw_idx(i, h)] = V[(size_t)i * H_ + h];
        }
        // W transpose via LDS, *log2e
#pragma unroll
        for (int j = 0; j < 4; ++j) {
            int h = h0 + ty + j * 8;
            int i = i0 + tx;
            float v = 0.f;
            if (i < D_) v = W[(size_t)h * D_ + i] * LOG2E;
            smem[(ty + j * 8) * 33 + tx] = v;
        }
        __syncthreads();
#pragma unroll
        for (int j = 0; j < 4; ++j) {
            int i = i0 + ty + j * 8;
            int h = h0 + tx;
            if (i < D_) VWs[vw_idx(i, h) + 256] = smem[tx * 33 + ty + j * 8];
        }
    } else {
        float* xs = smem;          // [4][64]
        float* ws = smem + 256;    // [4][64]
        int idx = blockIdx.x - 800;
        int r   = idx >> 8;                       // 0..4
        int b0  = (idx & 15) * 64;
        int h0  = ((idx >> 4) & 15) * 64;
        int j0s = seg_bound(r), j1s = seg_bound(r + 1);

        const int tb = t >> 4, th = t & 15;       // 16x16, each 4b x 4h
        float acc[4][4];
#pragma unroll
        for (int bi = 0; bi < 4; ++bi)
#pragma unroll
            for (int hh = 0; hh < 4; ++hh) acc[bi][hh] = 0.f;

        for (int j0 = j0s; j0 < j1s; j0 += 4) {
            float xv = px[(size_t)(b0 + (t >> 2)) * D_ + j0 + (t & 3)];
            float4 wv = make_float4(0, 0, 0, 0);
            if (t < 64) wv = *(const float4*)(W + (size_t)(h0 + t) * D_ + j0);
            __syncthreads();
            xs[(t & 3) * 64 + (t >> 2)] = xv;
            if (t < 64) {
                ws[0 * 64 + t] = wv.x * LOG2E;
                ws[1 * 64 + t] = wv.y * LOG2E;
                ws[2 * 64 + t] = wv.z * LOG2E;
                ws[3 * 64 + t] = wv.w * LOG2E;
            }
            __syncthreads();
#pragma unroll
            for (int jj = 0; jj < 4; ++jj) {
                float4 xb = *(float4*)&xs[jj * 64 + tb * 4];
                float4 wb = *(float4*)&ws[jj * 64 + th * 4];
                float xa[4] = {xb.x, xb.y, xb.z, xb.w};
                float wa[4] = {wb.x, wb.y, wb.z, wb.w};
#pragma unroll
                for (int bi = 0; bi < 4; ++bi)
#pragma unroll
                    for (int hh = 0; hh < 4; ++hh)
                        acc[bi][hh] = fmaf(xa[bi], wa[hh], acc[bi][hh]);
            }
        }
        float* dst = G + (size_t)r * BH_;
#pragma unroll
        for (int bi = 0; bi < 4; ++bi) {
            float4 o = make_float4(acc[bi][0], acc[bi][1], acc[bi][2], acc[bi][3]);
            *(float4*)(dst + (size_t)(b0 + tb * 4 + bi) * H_ + h0 + th * 4) = o;
        }
    }
}

// ---------- DPP reduce: both 32-lane halves simultaneously ----------
template <int CTRL>
__device__ __forceinline__ float dpp_add(float p) {
    int s = __builtin_amdgcn_update_dpp(0, __float_as_int(p), CTRL, 0xf, 0xf, true);
    return p + __int_as_float(s);
}
__device__ __forceinline__ float reduce_halves(float p) {
    p = dpp_add<0x111>(p);
    p = dpp_add<0x112>(p);
    p = dpp_add<0x114>(p);
    p = dpp_add<0x118>(p);
    p = dpp_add<0x142>(p);   // lane31 = sum(0..31), lane63 = sum(32..63)
    return p;
}

// ---------- main scan: blocks share (s,hb); LDS-staged VW; pk-exp2 ----------
__global__ __launch_bounds__(256, 6) void nade_main(
    const float* __restrict__ px,   // [B, D]
    const float* __restrict__ c,    // [H]
    const float* __restrict__ VWs,  // step images
    const float* __restrict__ G,    // [5][B][H] (log2 domain)
    float* __restrict__ part)       // [4][B][D]
{
    __shared__ float lds[3 * 2048];             // 3 bufs x (4 steps x 512 floats) = 24 KB

    const int lane = threadIdx.x & 63;
    const int wid  = threadIdx.x >> 6;
    const int bid  = blockIdx.x;
    const int s    = bid % 6;
    const int t2   = bid / 6;                   // 0..511
    const int hb   = t2 & 3;
    const int rpg  = t2 >> 2;                   // 0..127
    const int half = lane >> 5;
    const int hl   = lane & 31;
    const int row  = rpg * 8 + wid * 2 + half;
    const int h0   = hb * 256 + hl * 8;

    const int i0s = seg_bound(s), i1s = seg_bound(s + 1);
    const int nchunk = (i1s - i0s) >> 2;

    // A (log2 domain) = c*log2e + sum_{r<s} G_r, held as 4 v2f pairs
    v2f A01, A23, A45, A67;
    {
        float4 c0 = *(const float4*)(c + h0);
        float4 c1 = *(const float4*)(c + h0 + 4);
        A01 = (v2f){c0.x * LOG2E, c0.y * LOG2E};
        A23 = (v2f){c0.z * LOG2E, c0.w * LOG2E};
        A45 = (v2f){c1.x * LOG2E, c1.y * LOG2E};
        A67 = (v2f){c1.z * LOG2E, c1.w * LOG2E};
        for (int r = 0; r < s; ++r) {
            const float* gp = G + (size_t)r * BH_ + (size_t)row * H_ + h0;
            float4 g0 = *(const float4*)(gp);
            float4 g1 = *(const float4*)(gp + 4);
            A01 = pk_add(A01, (v2f){g0.x, g0.y});
            A23 = pk_add(A23, (v2f){g0.z, g0.w});
            A45 = pk_add(A45, (v2f){g1.x, g1.y});
            A67 = pk_add(A67, (v2f){g1.z, g1.w});
        }
    }

    const float* xp = px + (size_t)row * D_;
    float*       pp = part + ((size_t)hb * B_ + row) * D_;

    // stage wave-wid's step of a chunk (2 x 1KB granules) into LDS buf
    auto stage = [&](int step, int bufidx) {
        const float* src = VWs + (((size_t)step * 4 + hb) << 9) + lane * 4;
        float* dst = &lds[bufidx * 2048 + wid * 512 + lane * 4];
        __builtin_amdgcn_global_load_lds((__attribute__((address_space(1))) void*)(src),
                                         (__attribute__((address_space(3))) void*)(dst), 16, 0, 0);
        __builtin_amdgcn_global_load_lds((__attribute__((address_space(1))) void*)(src + 256),
                                         (__attribute__((address_space(3))) void*)(dst + 256), 16, 0, 0);
    };

    // one step (8 h): pk soft-exp2 + one rcp per 8
    auto step8 = [&](float4 v0f, float4 v1f, float4 w0f, float4 w1f, float xi) -> float {
        v2f t0, t1, t2, t3;
        t0.x = __builtin_amdgcn_fmed3f(-A01.x, -126.f, 15.f);
        t0.y = __builtin_amdgcn_fmed3f(-A01.y, -126.f, 15.f);
        t1.x = __builtin_amdgcn_fmed3f(-A23.x, -126.f, 15.f);
        t1.y = __builtin_amdgcn_fmed3f(-A23.y, -126.f, 15.f);
        t2.x = __builtin_amdgcn_fmed3f(-A45.x, -126.f, 15.f);
        t2.y = __builtin_amdgcn_fmed3f(-A45.y, -126.f, 15.f);
        t3.x = __builtin_amdgcn_fmed3f(-A67.x, -126.f, 15.f);
        t3.y = __builtin_amdgcn_fmed3f(-A67.y, -126.f, 15.f);
        v2f one = {1.f, 1.f};
        v2f q0 = pk_add(exp2_pk(t0), one);
        v2f q1 = pk_add(exp2_pk(t1), one);
        v2f q2 = pk_add(exp2_pk(t2), one);
        v2f q3 = pk_add(exp2_pk(t3), one);
        v2f xx = {xi, xi};
        A01 = pk_fma((v2f){w0f.x, w0f.y}, xx, A01);
        A23 = pk_fma((v2f){w0f.z, w0f.w}, xx, A23);
        A45 = pk_fma((v2f){w1f.x, w1f.y}, xx, A45);
        A67 = pk_fma((v2f){w1f.z, w1f.w}, xx, A67);
        float a01 = fmaf(v0f.x, q0.y, v0f.y * q0.x);
        float a23 = fmaf(v0f.z, q1.y, v0f.w * q1.x);
        float a45 = fmaf(v1f.x, q2.y, v1f.y * q2.x);
        float a67 = fmaf(v1f.z, q3.y, v1f.w * q3.x);
        float q01 = q0.x * q0.y, q23 = q1.x * q1.y;
        float q45 = q2.x * q2.y, q67 = q3.x * q3.y;
        float n0123 = fmaf(a01, q23, a23 * q01);
        float n4567 = fmaf(a45, q67, a67 * q45);
        float q0123 = q01 * q23, q4567 = q45 * q67;
        float r = __builtin_amdgcn_rcpf(q0123 * q4567);
        float n = fmaf(n0123, q4567, n4567 * q0123);
        return n * r;
    };

    // pre-stage chunks 0 and 1
    stage(i0s + wid, 0);
    stage(i0s + 4 + wid, 1);
    __syncthreads();

    float4 xq = *(const float4*)(xp + i0s);

    for (int ck = 0; ck < nchunk; ++ck) {
        const int ib = i0s + ck * 4;
        if (ck + 2 < nchunk) stage(ib + 8 + wid, (ck + 2) % 3);
        float4 xq_n = (ck + 1 < nchunk) ? *(const float4*)(xp + ib + 4) : xq;

        const float* bufp = &lds[(ck % 3) * 2048 + hl * 4];
        float xa[4] = {xq.x, xq.y, xq.z, xq.w};
        float pr[4];
#pragma unroll
        for (int j = 0; j < 4; ++j) {
            const float* base = bufp + j * 512;
            float4 v0 = *(const float4*)(base);
            float4 v1 = *(const float4*)(base + 128);
            float4 w0 = *(const float4*)(base + 256);
            float4 w1 = *(const float4*)(base + 384);
            pr[j] = reduce_halves(step8(v0, v1, w0, w1, xa[j]));
        }
        if (hl == 31) *(float4*)(pp + ib) = make_float4(pr[0], pr[1], pr[2], pr[3]);
        xq = xq_n;
        __syncthreads();
    }
}

// ---------- epilogue: out[row][i] = bias[i] + sum_hb part[hb][row][i] ----------
__global__ __launch_bounds__(256) void reduce_out(const float* __restrict__ part,
                                                  const float* __restrict__ bias,
                                                  float* __restrict__ out) {
    int t = blockIdx.x * 256 + threadIdx.x;
    if (t >= B_ * (D_ / 4)) return;
    int row = t / (D_ / 4);
    int ic  = (t - row * (D_ / 4)) * 4;
    float4 acc = *(const float4*)(bias + ic);
    const float* p = part + (size_t)row * D_ + ic;
#pragma unroll
    for (int hb = 0; hb < 4; ++hb) {
        float4 v = *(const float4*)(p + (size_t)hb * B_ * D_);
        acc.x += v.x; acc.y += v.y; acc.z += v.z; acc.w += v.w;
    }
    *(float4*)(out + (size_t)row * D_ + ic) = acc;
}

extern "C" void kernel_launch(void* const* d_in, const int* in_sizes, int n_in,
                              void* d_out, int out_size, void* d_ws, size_t ws_size,
                              hipStream_t stream) {
    const float* px   = (const float*)d_in[0];  // [B, D]
    const float* W    = (const float*)d_in[1];  // [H, D]
    const float* c    = (const float*)d_in[2];  // [H]
    const float* V    = (const float*)d_in[3];  // [D, H]
    const float* bias = (const float*)d_in[4];  // [D]
    float* out = (float*)d_out;                 // [B, D]

    float* VWs  = (float*)d_ws;                 // [792][4][512] floats
    float* G    = VWs + (size_t)792 * 2048;     // [5][B][H]
    float* part = G + (size_t)5 * BH_;          // [4][B][D]

    prep<<<dim3(2080), 256, 0, stream>>>(V, W, px, VWs, G);

    // 3072 blocks x 4 waves; block shares (s,hb) across its 4 row-pair waves
    nade_main<<<dim3(3072), 256, 0, stream>>>(px, c, VWs, G, part);

    reduce_out<<<dim3((B_ * (D_ / 4) + 255) / 256), 256, 0, stream>>>(part, bias, out);
}